// Round 15
// baseline (350.280 us; speedup 1.0000x reference)
//
#include <hip/hip_runtime.h>
#include <math.h>

#define BATCH 16
#define SEQLEN 4096
#define INPUT_DIM 57
#define D_MODEL 256
#define D_INNER 512
#define D_STATE 8
#define HEADDIM 16
#define NHEADS 32
#define CHUNK 8
#define NC (SEQLEN/CHUNK)          // 512
#define CONV_DIM 528
#define D_INPROJ 1072
#define OUT_SIZE 6
#define NTOK (BATCH*SEQLEN)        // 65536
#define SEG 32                     // chunks per scan segment
#define NSEG (NC/SEG)              // 16

static __device__ const int tri_i_tab[36] = {0,1,1,2,2,2,3,3,3,3,4,4,4,4,4,5,5,5,5,5,5,6,6,6,6,6,6,6,7,7,7,7,7,7,7,7};
static __device__ const int tri_j_tab[36] = {0,0,1,0,1,2,0,1,2,3,0,1,2,3,4,0,1,2,3,4,5,0,1,2,3,4,5,6,0,1,2,3,4,5,6,7};

__device__ __forceinline__ unsigned short f2bf(float f) {   // RNE bf16, finite
    unsigned v = __float_as_uint(f);
    return (unsigned short)((v + 0x7fffu + ((v >> 16) & 1u)) >> 16);
}

typedef __attribute__((ext_vector_type(8))) short bf16x8;
typedef __attribute__((ext_vector_type(4))) float f32x4;

// ---------------------------------------------------------------------------
// P0: fold W_in into W_inproj; fold W_out into W_cls; emit bf16 Wbf[n][k].
// ---------------------------------------------------------------------------
__global__ void precompute_kernel(const float* __restrict__ W_in,
                                  const float* __restrict__ b_in,
                                  const float* __restrict__ W_inproj,
                                  const float* __restrict__ W_out,
                                  const float* __restrict__ W_cls,
                                  float* __restrict__ WcT,    // [57][1072]
                                  float* __restrict__ b_comb, // [1072]
                                  unsigned short* __restrict__ Wbf, // [1024][64]
                                  float* __restrict__ W_oc)   // [6][512]
{
    int blk = blockIdx.x;
    int t = threadIdx.x;
    if (blk < D_INPROJ) {
        int n = blk;
        if (t < INPUT_DIM) {
            double acc = 0.0;
            for (int m = 0; m < D_MODEL; ++m)
                acc += (double)W_inproj[n*D_MODEL+m] * (double)W_in[m*INPUT_DIM+t];
            WcT[t*D_INPROJ + n] = (float)acc;
            if (n < 1024) Wbf[n*64 + t] = f2bf((float)acc);
        } else {
            if (t == INPUT_DIM) {
                double acc = 0.0;
                for (int m = 0; m < D_MODEL; ++m)
                    acc += (double)W_inproj[n*D_MODEL+m] * (double)b_in[m];
                b_comb[n] = (float)acc;
            }
            if (n < 1024 && t < 64) Wbf[n*64 + t] = 0;   // k pad 57..63
        }
    } else {
        int d = blk - D_INPROJ;
        if (t < OUT_SIZE) {
            double acc = 0.0;
            for (int m = 0; m < D_MODEL; ++m)
                acc += (double)W_cls[t*D_MODEL+m] * (double)W_out[m*D_INNER+d];
            W_oc[t*D_INNER + d] = (float)acc;
        }
    }
}

// ---------------------------------------------------------------------------
// FUSED v2.2: v2.1 + Bs/Cs hoisted into registers before the tile loop
// (they are tile-invariant; previously re-read 8x = 512 ds_read_b32/thread).
// Bs/Cs rows padded to 12 floats so float4 reads are aligned + conflict-free.
// ---------------------------------------------------------------------------
__global__ __launch_bounds__(256) void fused_kernel(
    const float* __restrict__ x,            // [NTOK][57]
    const unsigned short* __restrict__ Wbf, // [1024][64] bf16
    const float* __restrict__ WcT,          // [57][1072] fp32
    const float* __restrict__ bcomb,        // [1072]
    const float* __restrict__ conv_w,       // [528][4]
    const float* __restrict__ conv_b,       // [528]
    const float* __restrict__ dt_bias,      // [32]
    const float* __restrict__ A_log,        // [32]
    const float* __restrict__ Dvec,         // [32]
    unsigned* __restrict__ SGg,             // [B*NC][32][128] packed lo=S hi=g
    float* __restrict__ cdec,               // [B*NC][32]
    float* __restrict__ partial_intra)      // [B*NC][512]
{
    union SU {   // xs dead after A-frag load + phase 2b; tables written in 4b
        float xs[32][68];                               // 8704 B
        struct { float scl[2][36][33]; float gco[2][8][33]; } t; // 11616 B
    };
    __shared__ __attribute__((aligned(16))) SU u;
    __shared__ float ex[19][48];               // B/C/dt fp32, rows t0-3..t0+15
    __shared__ __attribute__((aligned(16))) float Bs[2][8][12], Cs[2][8][12];
    __shared__ float dts[2][8][33], cAl[2][8][33], els[2][8][33];
    __shared__ float CBl[2][8][8];

    const int blk = blockIdx.x;
    const int b = blk >> 8, cp = blk & 255;
    const int bc0 = (b << 9) + cp*2;           // chunk index of chunk 0
    const int tid = threadIdx.x;
    const long t0 = (long)b*SEQLEN + (long)cp*16;
    const bool first = (cp == 0);

    // ---- phase 1: stage 32 x rows (t0-16 .. t0+15), k padded ----
    #pragma unroll
    for (int it = 0; it < 8; ++it) {
        int idx = tid + it*256;
        int r = idx >> 6, k = idx & 63;
        float v = 0.f;
        if (k < INPUT_DIM && (r >= 16 || !first))
            v = x[(t0 - 16 + r)*INPUT_DIM + k];
        u.xs[r][k] = v;
    }
    __syncthreads();

    const int lane = tid & 63, wv = tid >> 6;
    const int quad = lane >> 4, mrow = lane & 15;

    // A fragments (regs; survive table overwrite of xs)
    bf16x8 aM[2], aH[2];
    #pragma unroll
    for (int hf = 0; hf < 2; ++hf) {
        const float* sm = &u.xs[16 + mrow][hf*32 + quad*8];
        const float* sh = &u.xs[mrow][hf*32 + quad*8];
        #pragma unroll
        for (int j = 0; j < 8; ++j) {
            aM[hf][j] = (short)f2bf(sm[j]);
            aH[hf][j] = (short)f2bf(sh[j]);
        }
    }

    // ---- phase 2b: fp32 extras (48 cols x 19 rows, K=57) ----
    if (tid < 192) {
        const int col = tid % 48;
        const int grp = tid / 48;              // 0..3
        const int r0 = grp*5;
        const int nr = (grp == 3) ? 4 : 5;
        const float be = bcomb[1024 + col];
        float a[5];
        #pragma unroll
        for (int j = 0; j < 5; ++j) a[j] = be;
        for (int k = 0; k < INPUT_DIM; ++k) {
            const float w = WcT[(size_t)k*D_INPROJ + 1024 + col];
            #pragma unroll
            for (int j = 0; j < 5; ++j)
                if (j < nr) a[j] += w*u.xs[13 + r0 + j][k];
        }
        #pragma unroll
        for (int j = 0; j < 5; ++j) {
            if (j < nr) {
                int r = r0 + j;
                ex[r][col] = (first && r < 3) ? 0.f : a[j];
            }
        }
    }
    __syncthreads();   // ex visible; xs reads done (A-frags in regs)

    // ---- phase 3: B/C conv+silu (32 lanes) and dt chain (64 lanes) ----
    if (tid < 32) {
        const int cw = tid >> 4, q = tid & 15;
        const int ch = 512 + q;
        const float4 cw4 = *(const float4*)&conv_w[ch*4];
        const float cb = conv_b[ch];
        float s0 = ex[cw*8+0][q], s1 = ex[cw*8+1][q], s2 = ex[cw*8+2][q];
        #pragma unroll
        for (int i = 0; i < 8; ++i) {
            float s3 = ex[cw*8+i+3][q];
            float v = cb + s0*cw4.x + s1*cw4.y + s2*cw4.z + s3*cw4.w;
            v = v / (1.f + __expf(-v));
            if (q < 8) Bs[cw][i][q] = v; else Cs[cw][i][q-8] = v;
            s0 = s1; s1 = s2; s2 = s3;
        }
    } else if (tid >= 64 && tid < 128) {
        const int cw = (tid - 64) >> 5, h = (tid - 64) & 31;
        const float Ah = -__expf(A_log[h]);
        const float db = dt_bias[h];
        float ca = 0.f, e = 1.f;
        #pragma unroll
        for (int i = 0; i < 8; ++i) {
            float raw = ex[cw*8 + i + 3][16 + h] + db;
            float dt = (raw > 20.f) ? raw : log1pf(__expf(raw));
            dts[cw][i][h] = dt;
            ca += dt * Ah;
            cAl[cw][i][h] = ca;
            e = __expf(ca);
            els[cw][i][h] = e;
        }
        cdec[(bc0+cw)*32 + h] = e;
    }
    __syncthreads();

    // ---- phase 4: CB = C B^T per chunk ----
    if (tid < 128) {
        const int cw = tid >> 6, i = (tid >> 3) & 7, j = tid & 7;
        float s = 0.f;
        #pragma unroll
        for (int n = 0; n < 8; ++n) s += Cs[cw][i][n]*Bs[cw][j][n];
        CBl[cw][i][j] = s;
    }
    __syncthreads();

    // ---- phase 4b: coefficient tables (scl triangle + gco), into union ----
    #pragma unroll
    for (int q = 0; q < 9; ++q) {
        int idx = tid + q*256;                 // 2304 = 2*36*32
        int cw2 = idx / 1152, rem = idx - cw2*1152;
        int pr = rem >> 5, h2 = rem & 31;
        int i = tri_i_tab[pr], j = tri_j_tab[pr];
        u.t.scl[cw2][pr][h2] = CBl[cw2][i][j]
            * __expf(cAl[cw2][i][h2] - cAl[cw2][j][h2]) * dts[cw2][j][h2];
    }
    #pragma unroll
    for (int q = 0; q < 2; ++q) {
        int idx = tid + q*256;                 // 512 = 2*8*32
        int cw2 = idx >> 8, rem = idx & 255;
        int j = rem >> 5, h2 = rem & 31;
        u.t.gco[cw2][j][h2] = __expf(cAl[cw2][7][h2] - cAl[cw2][j][h2]) * dts[cw2][j][h2];
    }
    __syncthreads();

    // ---- phase 5: barrier-free tile loop. Lane owns z col `col` and x col
    // `col+512`, rows quad*4..quad*4+3. cw = quad>>1; joff = (quad&1)*4. ----
    const int cw   = quad >> 1;
    const int joff = (quad & 1) * 4;
    const int srcConv = (lane + 48) & 63;      // lane - 16 (mod 64)

    // hoist tile-invariant Bs/Cs rows into registers (was 512 ds reads/thread)
    float Br[4][8], Cr[4][8];
    #pragma unroll
    for (int r = 0; r < 4; ++r) {
        const int il = joff + r;
        *(float4*)&Br[r][0] = *(const float4*)&Bs[cw][il][0];
        *(float4*)&Br[r][4] = *(const float4*)&Bs[cw][il][4];
        *(float4*)&Cr[r][0] = *(const float4*)&Cs[cw][il][0];
        *(float4*)&Cr[r][4] = *(const float4*)&Cs[cw][il][4];
    }

    #pragma unroll
    for (int t = 0; t < 8; ++t) {
        const int g   = wv + 4*t;              // 0..31 = head h
        const int h   = g;
        const int col = g*16 + mrow;           // z col; x col = col+512

        // z MFMA
        const unsigned short* wpz = &Wbf[(size_t)col*64];
        bf16x8 bz0 = *(const bf16x8*)&wpz[quad*8];
        bf16x8 bz1 = *(const bf16x8*)&wpz[32 + quad*8];
        const float bvz = bcomb[col];
        f32x4 accZ; accZ.x = bvz; accZ.y = bvz; accZ.z = bvz; accZ.w = bvz;
        accZ = __builtin_amdgcn_mfma_f32_16x16x32_bf16(aM[0], bz0, accZ, 0, 0, 0);
        accZ = __builtin_amdgcn_mfma_f32_16x16x32_bf16(aM[1], bz1, accZ, 0, 0, 0);

        // x MFMA: main + halo
        const unsigned short* wpx = &Wbf[(size_t)(col + 512)*64];
        bf16x8 bx0 = *(const bf16x8*)&wpx[quad*8];
        bf16x8 bx1 = *(const bf16x8*)&wpx[32 + quad*8];
        const float bvx = bcomb[col + 512];
        f32x4 accXM; accXM.x = bvx; accXM.y = bvx; accXM.z = bvx; accXM.w = bvx;
        accXM = __builtin_amdgcn_mfma_f32_16x16x32_bf16(aM[0], bx0, accXM, 0, 0, 0);
        accXM = __builtin_amdgcn_mfma_f32_16x16x32_bf16(aM[1], bx1, accXM, 0, 0, 0);
        f32x4 accXH; accXH.x = bvx; accXH.y = bvx; accXH.z = bvx; accXH.w = bvx;
        accXH = __builtin_amdgcn_mfma_f32_16x16x32_bf16(aH[0], bx0, accXH, 0, 0, 0);
        accXH = __builtin_amdgcn_mfma_f32_16x16x32_bf16(aH[1], bx1, accXH, 0, 0, 0);

        // conv halo: consumer quad q gets rows 4q-1,-2,-3 from lane-16
        float s1 = (quad == 3) ? accXH[3] : accXM[3];
        float s2 = (quad == 3) ? accXH[2] : accXM[2];
        float s3 = (quad == 3) ? accXH[1] : accXM[1];
        float r1 = __shfl(s1, srcConv, 64);
        float r2 = __shfl(s2, srcConv, 64);
        float r3 = __shfl(s3, srcConv, 64);
        if (first && quad == 0) { r1 = 0.f; r2 = 0.f; r3 = 0.f; }

        const float4 cw4 = *(const float4*)&conv_w[col*4];   // conv channel = col
        const float cb = conv_b[col];
        float vals[7] = {r3, r2, r1, accXM[0], accXM[1], accXM[2], accXM[3]};
        float xv[4], szv[4];
        #pragma unroll
        for (int r = 0; r < 4; ++r) {
            float v = cb + vals[r]*cw4.x + vals[r+1]*cw4.y + vals[r+2]*cw4.z + vals[r+3]*cw4.w;
            xv[r] = v / (1.f + __expf(-v));
            float z = accZ[r];
            szv[r] = z / (1.f + __expf(-z));
        }

        // attention partials for all 8 chunk rows over own 4 j's
        float part[8];
        #pragma unroll
        for (int i = 0; i < 8; ++i) {
            float p = 0.f;
            #pragma unroll
            for (int r = 0; r < 4; ++r) {
                int jl = joff + r;
                if (jl <= i)
                    p += u.t.scl[cw][(i*(i+1))/2 + jl][h] * xv[r];
            }
            part[i] = p;
        }

        // combine with quad partner; pooled intra
        const float Dv = Dvec[h];
        float pa = 0.f;
        #pragma unroll
        for (int r = 0; r < 4; ++r) {
            float mine   = (quad & 1) ? part[4+r] : part[r];
            float theirs = (quad & 1) ? part[r]   : part[4+r];
            float other  = __shfl_xor(theirs, 16, 64);
            float y = Dv*xv[r] + mine + other;
            pa += y * szv[r];
        }
        pa += __shfl_xor(pa, 16, 64);
        if ((quad & 1) == 0)
            partial_intra[(size_t)(bc0 + cw)*512 + col] = pa;

        // (S, g) partials over own 4 rows; bf16-packed xor-combine (8 shfl)
        float sn[8], gg[8];
        #pragma unroll
        for (int n = 0; n < 8; ++n) { sn[n] = 0.f; gg[n] = 0.f; }
        #pragma unroll
        for (int r = 0; r < 4; ++r) {
            const int il = joff + r;
            float gc = u.t.gco[cw][il][h];
            float e  = els[cw][il][h];
            float w  = szv[r]*e;
            float uu = gc*xv[r];
            #pragma unroll
            for (int n = 0; n < 8; ++n) {
                sn[n] += uu*Br[r][n];
                gg[n] += w*Cr[r][n];
            }
        }
        unsigned up[8];
        #pragma unroll
        for (int n = 0; n < 8; ++n) {
            unsigned pk = ((unsigned)f2bf(gg[n]) << 16) | f2bf(sn[n]);
            unsigned pv = (unsigned)__shfl_xor((int)pk, 16, 64);
            float psn = __uint_as_float(pv << 16);
            float pgg = __uint_as_float(pv & 0xffff0000u);
            up[n] = ((unsigned)f2bf(gg[n] + pgg) << 16) | f2bf(sn[n] + psn);
        }
        if ((quad & 1) == 0) {
            unsigned* dst = &SGg[((size_t)(bc0 + cw)*32 + h)*128 + mrow*8];
            *(uint4*)&dst[0] = *(uint4*)&up[0];
            *(uint4*)&dst[4] = *(uint4*)&up[4];
        }
    }
}

// ---------------------------------------------------------------------------
// A2 pass 1: element-parallel segmented scan (full batch). Zero barriers/LDS.
// ---------------------------------------------------------------------------
__global__ __launch_bounds__(128) void scanseg_kernel(
    const unsigned* __restrict__ SGg,  // [B*NC][32][128] packed
    const float* __restrict__ cdec,    // [B*NC][32]
    float* __restrict__ Sloc,          // [8192][128]
    float* __restrict__ Gseg,
    float* __restrict__ Aseg,
    float* __restrict__ ploc)          // [8192][16]
{
    const int blk = blockIdx.x;             // (b*32+h)*NSEG + seg
    const int seg = blk & (NSEG-1);
    const int bh  = blk >> 4;
    const int b = bh >> 5, h = bh & 31;
    const int tid = threadIdx.x;
    const int c0 = seg*SEG;

    float s = 0.f, P = 1.f, G = 0.f, pooled = 0.f;
    const unsigned* src = &SGg[((size_t)(b*NC + c0)*32 + h)*128 + tid];
    const float* dsrc = &cdec[(b*NC + c0)*32 + h];

    #pragma unroll 4
    for (int cc = 0; cc < SEG; ++cc) {
        unsigned u = src[(size_t)cc*4096];
        float d = dsrc[cc*32];
        float Sv = __uint_as_float(u << 16);
        float gv = __uint_as_float(u & 0xffff0000u);
        pooled += s * gv;
        G += P * gv;
        P *= d;
        s = s*d + Sv;
    }
    Sloc[(size_t)blk*128 + tid] = s;
    Gseg[(size_t)blk*128 + tid] = G;
    if (tid == 0) Aseg[blk] = P;

    float t = pooled;
    t += __shfl_down(t, 4, 8);
    t += __shfl_down(t, 2, 8);
    t += __shfl_down(t, 1, 8);
    if ((tid & 7) == 0) ploc[(size_t)blk*16 + (tid >> 3)] = t;
}

// ---------------------------------------------------------------------------
// A2 pass 2: combine NSEG segments per (b,h).
// ---------------------------------------------------------------------------
__global__ __launch_bounds__(128) void scancomb_kernel(
    const float* __restrict__ Sloc,
    const float* __restrict__ Gseg,
    const float* __restrict__ Aseg,
    const float* __restrict__ ploc,
    double* __restrict__ partial_inter) // [B][512]
{
    __shared__ double red[128];
    const int bh = blockIdx.x;              // b*32 + h
    const int tid = threadIdx.x;
    float s = 0.f;
    double acc = 0.0;
    for (int seg = 0; seg < NSEG; ++seg) {
        size_t base = (size_t)(bh*NSEG + seg);
        float Gv = Gseg[base*128 + tid];
        float Av = Aseg[base];
        float Sv = Sloc[base*128 + tid];
        acc += (double)(s * Gv);
        s = s*Av + Sv;
    }
    red[tid] = acc;
    __syncthreads();
    if (tid < 16) {
        double t = 0.0;
        #pragma unroll
        for (int n = 0; n < 8; ++n) t += red[tid*8 + n];
        for (int seg = 0; seg < NSEG; ++seg)
            t += (double)ploc[(size_t)(bh*NSEG + seg)*16 + tid];
        partial_inter[(size_t)bh*16 + tid] = t;
    }
}

// ---------------------------------------------------------------------------
__global__ __launch_bounds__(256) void reduce_intra_kernel(
    const float* __restrict__ pIn,     // [B*NC][512]
    float* __restrict__ pred)          // [B][32][512]
{
    const int g = blockIdx.x & 31;
    const int b = blockIdx.x >> 5;
    const int tid = threadIdx.x;
    for (int col = tid; col < 512; col += 256) {
        float s = 0.f;
        #pragma unroll 4
        for (int c = 0; c < 16; ++c)
            s += pIn[((size_t)b*NC + g*16 + c)*512 + col];
        pred[((size_t)(b*32) + g)*512 + col] = s;
    }
}

// ---------------------------------------------------------------------------
__global__ __launch_bounds__(512) void final_kernel(
    const float* __restrict__ pred,           // [B][32][512]
    const double* __restrict__ partial_inter, // [B][512]
    const float* __restrict__ W_oc,           // [6][512]
    const float* __restrict__ b_cls,          // [6]
    float* __restrict__ out)                  // [B][6]
{
    __shared__ double pooled[512];
    const int b = blockIdx.x, tid = threadIdx.x;
    double ssum = 0.0;
    for (int g = 0; g < 32; ++g)
        ssum += (double)pred[((size_t)(b*32) + g)*512 + tid];
    ssum += partial_inter[(size_t)b*512 + tid];
    pooled[tid] = ssum * (1.0/(double)SEQLEN);
    __syncthreads();
    if (tid < OUT_SIZE*64) {
        const int o = tid >> 6, l = tid & 63;
        double acc = 0.0;
        for (int m = l; m < 512; m += 64)
            acc += pooled[m] * (double)W_oc[o*512 + m];
        #pragma unroll
        for (int off = 32; off > 0; off >>= 1)
            acc += __shfl_down(acc, off);
        if (l == 0) out[b*OUT_SIZE + o] = (float)(acc + (double)b_cls[o]);
    }
}

// ---------------------------------------------------------------------------
extern "C" void kernel_launch(void* const* d_in, const int* in_sizes, int n_in,
                              void* d_out, int out_size, void* d_ws, size_t ws_size,
                              hipStream_t stream)
{
    const float* x        = (const float*)d_in[0];
    const float* W_in     = (const float*)d_in[1];
    const float* b_in     = (const float*)d_in[2];
    const float* W_inproj = (const float*)d_in[3];
    const float* conv_w   = (const float*)d_in[4];
    const float* conv_b   = (const float*)d_in[5];
    const float* dt_bias  = (const float*)d_in[6];
    const float* A_log    = (const float*)d_in[7];
    const float* Dvec     = (const float*)d_in[8];
    const float* W_out    = (const float*)d_in[9];
    const float* W_cls    = (const float*)d_in[10];
    const float* b_cls    = (const float*)d_in[11];
    float* out = (float*)d_out;

    char* ws = (char*)d_ws;
    size_t off = 0;
    auto alloc = [&](size_t bytes) -> void* {
        void* p = ws + off;
        off += (bytes + 255) & ~(size_t)255;
        return p;
    };
    unsigned* SGg = (unsigned*)alloc((size_t)BATCH*NC*32*128*4);        // 134.2 MB
    float*  cdecb = (float*) alloc((size_t)BATCH*NC*32*4);              // 1.0 MB
    float*  pIn   = (float*) alloc((size_t)BATCH*NC*512*4);             // 16.8 MB
    float*  SlocB = (float*) alloc((size_t)BATCH*NHEADS*NSEG*128*4);    // 4.2 MB
    float*  GsegB = (float*) alloc((size_t)BATCH*NHEADS*NSEG*128*4);    // 4.2 MB
    float*  AsegB = (float*) alloc((size_t)BATCH*NHEADS*NSEG*4);
    float*  plocB = (float*) alloc((size_t)BATCH*NHEADS*NSEG*16*4);     // 0.5 MB
    float*  pred  = (float*) alloc((size_t)BATCH*32*512*4);             // 1.0 MB
    double* pIt   = (double*)alloc((size_t)BATCH*512*8);                // 64 KB
    float*  WcT   = (float*) alloc((size_t)INPUT_DIM*D_INPROJ*4);
    float*  bcomb = (float*) alloc((size_t)D_INPROJ*4);
    unsigned short* Wbf = (unsigned short*)alloc((size_t)1024*64*2);    // 128 KB
    float*  Woc   = (float*) alloc((size_t)OUT_SIZE*D_INNER*4);
    if (off > ws_size) return;   // diagnostic: absmax-fail instead of fault

    precompute_kernel<<<D_INPROJ + D_INNER, 64, 0, stream>>>(W_in, b_in, W_inproj, W_out, W_cls,
                                                             WcT, bcomb, Wbf, Woc);
    fused_kernel<<<BATCH*NC/2, 256, 0, stream>>>(x, Wbf, WcT, bcomb, conv_w, conv_b,
                                                 dt_bias, A_log, Dvec, SGg, cdecb, pIn);
    scanseg_kernel<<<BATCH*NHEADS*NSEG, 128, 0, stream>>>(SGg, cdecb, SlocB, GsegB, AsegB, plocB);
    scancomb_kernel<<<BATCH*NHEADS, 128, 0, stream>>>(SlocB, GsegB, AsegB, plocB, pIt);
    reduce_intra_kernel<<<BATCH*32, 256, 0, stream>>>(pIn, pred);
    final_kernel<<<BATCH, 512, 0, stream>>>(pred, pIt, Woc, b_cls, out);
}

// Round 16
// 329.400 us; speedup vs baseline: 1.0634x; 1.0634x over previous
//
#include <hip/hip_runtime.h>
#include <math.h>

#define BATCH 16
#define SEQLEN 4096
#define INPUT_DIM 57
#define D_MODEL 256
#define D_INNER 512
#define D_STATE 8
#define HEADDIM 16
#define NHEADS 32
#define CHUNK 8
#define NC (SEQLEN/CHUNK)          // 512
#define CONV_DIM 528
#define D_INPROJ 1072
#define OUT_SIZE 6
#define NTOK (BATCH*SEQLEN)        // 65536
#define SEG 32                     // chunks per scan segment
#define NSEG (NC/SEG)              // 16

static __device__ const int tri_i_tab[36] = {0,1,1,2,2,2,3,3,3,3,4,4,4,4,4,5,5,5,5,5,5,6,6,6,6,6,6,6,7,7,7,7,7,7,7,7};
static __device__ const int tri_j_tab[36] = {0,0,1,0,1,2,0,1,2,3,0,1,2,3,4,0,1,2,3,4,5,0,1,2,3,4,5,6,0,1,2,3,4,5,6,7};

__device__ __forceinline__ unsigned short f2bf(float f) {   // RNE bf16, finite
    unsigned v = __float_as_uint(f);
    return (unsigned short)((v + 0x7fffu + ((v >> 16) & 1u)) >> 16);
}

typedef __attribute__((ext_vector_type(8))) short bf16x8;
typedef __attribute__((ext_vector_type(4))) float f32x4;

// ---------------------------------------------------------------------------
// P0: fold W_in into W_inproj; fold W_out into W_cls; emit bf16 Wbf[n][k].
// ---------------------------------------------------------------------------
__global__ void precompute_kernel(const float* __restrict__ W_in,
                                  const float* __restrict__ b_in,
                                  const float* __restrict__ W_inproj,
                                  const float* __restrict__ W_out,
                                  const float* __restrict__ W_cls,
                                  float* __restrict__ WcT,    // [57][1072]
                                  float* __restrict__ b_comb, // [1072]
                                  unsigned short* __restrict__ Wbf, // [1024][64]
                                  float* __restrict__ W_oc)   // [6][512]
{
    int blk = blockIdx.x;
    int t = threadIdx.x;
    if (blk < D_INPROJ) {
        int n = blk;
        if (t < INPUT_DIM) {
            double acc = 0.0;
            for (int m = 0; m < D_MODEL; ++m)
                acc += (double)W_inproj[n*D_MODEL+m] * (double)W_in[m*INPUT_DIM+t];
            WcT[t*D_INPROJ + n] = (float)acc;
            if (n < 1024) Wbf[n*64 + t] = f2bf((float)acc);
        } else {
            if (t == INPUT_DIM) {
                double acc = 0.0;
                for (int m = 0; m < D_MODEL; ++m)
                    acc += (double)W_inproj[n*D_MODEL+m] * (double)b_in[m];
                b_comb[n] = (float)acc;
            }
            if (n < 1024 && t < 64) Wbf[n*64 + t] = 0;   // k pad 57..63
        }
    } else {
        int d = blk - D_INPROJ;
        if (t < OUT_SIZE) {
            double acc = 0.0;
            for (int m = 0; m < D_MODEL; ++m)
                acc += (double)W_cls[t*D_MODEL+m] * (double)W_out[m*D_INNER+d];
            W_oc[t*D_INNER + d] = (float)acc;
        }
    }
}

// ---------------------------------------------------------------------------
// FUSED v2.3: R14 (v2.1) structure, but the S/g inner loop reads Bs/Cs rows
// as aligned float4 pairs (16 ds_read_b128/tile instead of 64 ds_read_b32),
// with NO cross-tile register hoist (R15's hoist cost a VGPR tier: 48->76,
// occupancy 49->32%, regression). Transient row registers only.
// ---------------------------------------------------------------------------
__global__ __launch_bounds__(256) void fused_kernel(
    const float* __restrict__ x,            // [NTOK][57]
    const unsigned short* __restrict__ Wbf, // [1024][64] bf16
    const float* __restrict__ WcT,          // [57][1072] fp32
    const float* __restrict__ bcomb,        // [1072]
    const float* __restrict__ conv_w,       // [528][4]
    const float* __restrict__ conv_b,       // [528]
    const float* __restrict__ dt_bias,      // [32]
    const float* __restrict__ A_log,        // [32]
    const float* __restrict__ Dvec,         // [32]
    unsigned* __restrict__ SGg,             // [B*NC][32][128] packed lo=S hi=g
    float* __restrict__ cdec,               // [B*NC][32]
    float* __restrict__ partial_intra)      // [B*NC][512]
{
    union SU {   // xs dead after A-frag load + phase 2b; tables written in 4b
        float xs[32][68];                               // 8704 B
        struct { float scl[2][36][33]; float gco[2][8][33]; } t; // 11616 B
    };
    __shared__ __attribute__((aligned(16))) SU u;
    __shared__ float ex[19][48];               // B/C/dt fp32, rows t0-3..t0+15
    __shared__ __attribute__((aligned(16))) float Bs[2][8][12], Cs[2][8][12];
    __shared__ float dts[2][8][33], cAl[2][8][33], els[2][8][33];
    __shared__ float CBl[2][8][8];

    const int blk = blockIdx.x;
    const int b = blk >> 8, cp = blk & 255;
    const int bc0 = (b << 9) + cp*2;           // chunk index of chunk 0
    const int tid = threadIdx.x;
    const long t0 = (long)b*SEQLEN + (long)cp*16;
    const bool first = (cp == 0);

    // ---- phase 1: stage 32 x rows (t0-16 .. t0+15), k padded ----
    #pragma unroll
    for (int it = 0; it < 8; ++it) {
        int idx = tid + it*256;
        int r = idx >> 6, k = idx & 63;
        float v = 0.f;
        if (k < INPUT_DIM && (r >= 16 || !first))
            v = x[(t0 - 16 + r)*INPUT_DIM + k];
        u.xs[r][k] = v;
    }
    __syncthreads();

    const int lane = tid & 63, wv = tid >> 6;
    const int quad = lane >> 4, mrow = lane & 15;

    // A fragments (regs; survive table overwrite of xs)
    bf16x8 aM[2], aH[2];
    #pragma unroll
    for (int hf = 0; hf < 2; ++hf) {
        const float* sm = &u.xs[16 + mrow][hf*32 + quad*8];
        const float* sh = &u.xs[mrow][hf*32 + quad*8];
        #pragma unroll
        for (int j = 0; j < 8; ++j) {
            aM[hf][j] = (short)f2bf(sm[j]);
            aH[hf][j] = (short)f2bf(sh[j]);
        }
    }

    // ---- phase 2b: fp32 extras (48 cols x 19 rows, K=57) ----
    if (tid < 192) {
        const int col = tid % 48;
        const int grp = tid / 48;              // 0..3
        const int r0 = grp*5;
        const int nr = (grp == 3) ? 4 : 5;
        const float be = bcomb[1024 + col];
        float a[5];
        #pragma unroll
        for (int j = 0; j < 5; ++j) a[j] = be;
        for (int k = 0; k < INPUT_DIM; ++k) {
            const float w = WcT[(size_t)k*D_INPROJ + 1024 + col];
            #pragma unroll
            for (int j = 0; j < 5; ++j)
                if (j < nr) a[j] += w*u.xs[13 + r0 + j][k];
        }
        #pragma unroll
        for (int j = 0; j < 5; ++j) {
            if (j < nr) {
                int r = r0 + j;
                ex[r][col] = (first && r < 3) ? 0.f : a[j];
            }
        }
    }
    __syncthreads();   // ex visible; xs reads done (A-frags in regs)

    // ---- phase 3: B/C conv+silu (32 lanes) and dt chain (64 lanes) ----
    if (tid < 32) {
        const int cw = tid >> 4, q = tid & 15;
        const int ch = 512 + q;
        const float4 cw4 = *(const float4*)&conv_w[ch*4];
        const float cb = conv_b[ch];
        float s0 = ex[cw*8+0][q], s1 = ex[cw*8+1][q], s2 = ex[cw*8+2][q];
        #pragma unroll
        for (int i = 0; i < 8; ++i) {
            float s3 = ex[cw*8+i+3][q];
            float v = cb + s0*cw4.x + s1*cw4.y + s2*cw4.z + s3*cw4.w;
            v = v / (1.f + __expf(-v));
            if (q < 8) Bs[cw][i][q] = v; else Cs[cw][i][q-8] = v;
            s0 = s1; s1 = s2; s2 = s3;
        }
    } else if (tid >= 64 && tid < 128) {
        const int cw = (tid - 64) >> 5, h = (tid - 64) & 31;
        const float Ah = -__expf(A_log[h]);
        const float db = dt_bias[h];
        float ca = 0.f, e = 1.f;
        #pragma unroll
        for (int i = 0; i < 8; ++i) {
            float raw = ex[cw*8 + i + 3][16 + h] + db;
            float dt = (raw > 20.f) ? raw : log1pf(__expf(raw));
            dts[cw][i][h] = dt;
            ca += dt * Ah;
            cAl[cw][i][h] = ca;
            e = __expf(ca);
            els[cw][i][h] = e;
        }
        cdec[(bc0+cw)*32 + h] = e;
    }
    __syncthreads();

    // ---- phase 4: CB = C B^T per chunk ----
    if (tid < 128) {
        const int cw = tid >> 6, i = (tid >> 3) & 7, j = tid & 7;
        float s = 0.f;
        #pragma unroll
        for (int n = 0; n < 8; ++n) s += Cs[cw][i][n]*Bs[cw][j][n];
        CBl[cw][i][j] = s;
    }
    __syncthreads();

    // ---- phase 4b: coefficient tables (scl triangle + gco), into union ----
    #pragma unroll
    for (int q = 0; q < 9; ++q) {
        int idx = tid + q*256;                 // 2304 = 2*36*32
        int cw2 = idx / 1152, rem = idx - cw2*1152;
        int pr = rem >> 5, h2 = rem & 31;
        int i = tri_i_tab[pr], j = tri_j_tab[pr];
        u.t.scl[cw2][pr][h2] = CBl[cw2][i][j]
            * __expf(cAl[cw2][i][h2] - cAl[cw2][j][h2]) * dts[cw2][j][h2];
    }
    #pragma unroll
    for (int q = 0; q < 2; ++q) {
        int idx = tid + q*256;                 // 512 = 2*8*32
        int cw2 = idx >> 8, rem = idx & 255;
        int j = rem >> 5, h2 = rem & 31;
        u.t.gco[cw2][j][h2] = __expf(cAl[cw2][7][h2] - cAl[cw2][j][h2]) * dts[cw2][j][h2];
    }
    __syncthreads();

    // ---- phase 5: barrier-free tile loop. Lane owns z col `col` and x col
    // `col+512`, rows quad*4..quad*4+3. cw = quad>>1; joff = (quad&1)*4. ----
    const int cw   = quad >> 1;
    const int joff = (quad & 1) * 4;
    const int srcConv = (lane + 48) & 63;      // lane - 16 (mod 64)

    #pragma unroll
    for (int t = 0; t < 8; ++t) {
        const int g   = wv + 4*t;              // 0..31 = head h
        const int h   = g;
        const int col = g*16 + mrow;           // z col; x col = col+512

        // z MFMA
        const unsigned short* wpz = &Wbf[(size_t)col*64];
        bf16x8 bz0 = *(const bf16x8*)&wpz[quad*8];
        bf16x8 bz1 = *(const bf16x8*)&wpz[32 + quad*8];
        const float bvz = bcomb[col];
        f32x4 accZ; accZ.x = bvz; accZ.y = bvz; accZ.z = bvz; accZ.w = bvz;
        accZ = __builtin_amdgcn_mfma_f32_16x16x32_bf16(aM[0], bz0, accZ, 0, 0, 0);
        accZ = __builtin_amdgcn_mfma_f32_16x16x32_bf16(aM[1], bz1, accZ, 0, 0, 0);

        // x MFMA: main + halo
        const unsigned short* wpx = &Wbf[(size_t)(col + 512)*64];
        bf16x8 bx0 = *(const bf16x8*)&wpx[quad*8];
        bf16x8 bx1 = *(const bf16x8*)&wpx[32 + quad*8];
        const float bvx = bcomb[col + 512];
        f32x4 accXM; accXM.x = bvx; accXM.y = bvx; accXM.z = bvx; accXM.w = bvx;
        accXM = __builtin_amdgcn_mfma_f32_16x16x32_bf16(aM[0], bx0, accXM, 0, 0, 0);
        accXM = __builtin_amdgcn_mfma_f32_16x16x32_bf16(aM[1], bx1, accXM, 0, 0, 0);
        f32x4 accXH; accXH.x = bvx; accXH.y = bvx; accXH.z = bvx; accXH.w = bvx;
        accXH = __builtin_amdgcn_mfma_f32_16x16x32_bf16(aH[0], bx0, accXH, 0, 0, 0);
        accXH = __builtin_amdgcn_mfma_f32_16x16x32_bf16(aH[1], bx1, accXH, 0, 0, 0);

        // conv halo: consumer quad q gets rows 4q-1,-2,-3 from lane-16
        float s1 = (quad == 3) ? accXH[3] : accXM[3];
        float s2 = (quad == 3) ? accXH[2] : accXM[2];
        float s3 = (quad == 3) ? accXH[1] : accXM[1];
        float r1 = __shfl(s1, srcConv, 64);
        float r2 = __shfl(s2, srcConv, 64);
        float r3 = __shfl(s3, srcConv, 64);
        if (first && quad == 0) { r1 = 0.f; r2 = 0.f; r3 = 0.f; }

        const float4 cw4 = *(const float4*)&conv_w[col*4];   // conv channel = col
        const float cb = conv_b[col];
        float vals[7] = {r3, r2, r1, accXM[0], accXM[1], accXM[2], accXM[3]};
        float xv[4], szv[4];
        #pragma unroll
        for (int r = 0; r < 4; ++r) {
            float v = cb + vals[r]*cw4.x + vals[r+1]*cw4.y + vals[r+2]*cw4.z + vals[r+3]*cw4.w;
            xv[r] = v / (1.f + __expf(-v));
            float z = accZ[r];
            szv[r] = z / (1.f + __expf(-z));
        }

        // attention partials for all 8 chunk rows over own 4 j's
        float part[8];
        #pragma unroll
        for (int i = 0; i < 8; ++i) {
            float p = 0.f;
            #pragma unroll
            for (int r = 0; r < 4; ++r) {
                int jl = joff + r;
                if (jl <= i)
                    p += u.t.scl[cw][(i*(i+1))/2 + jl][h] * xv[r];
            }
            part[i] = p;
        }

        // combine with quad partner; pooled intra
        const float Dv = Dvec[h];
        float pa = 0.f;
        #pragma unroll
        for (int r = 0; r < 4; ++r) {
            float mine   = (quad & 1) ? part[4+r] : part[r];
            float theirs = (quad & 1) ? part[r]   : part[4+r];
            float other  = __shfl_xor(theirs, 16, 64);
            float y = Dv*xv[r] + mine + other;
            pa += y * szv[r];
        }
        pa += __shfl_xor(pa, 16, 64);
        if ((quad & 1) == 0)
            partial_intra[(size_t)(bc0 + cw)*512 + col] = pa;

        // (S, g) partials: per-row float4 Bs/Cs reads (transient regs only)
        float sn[8], gg[8];
        #pragma unroll
        for (int n = 0; n < 8; ++n) { sn[n] = 0.f; gg[n] = 0.f; }
        #pragma unroll
        for (int r = 0; r < 4; ++r) {
            const int il = joff + r;
            float gc = u.t.gco[cw][il][h];
            float e  = els[cw][il][h];
            float w  = szv[r]*e;
            float uu = gc*xv[r];
            const float4 B0 = *(const float4*)&Bs[cw][il][0];
            const float4 B1 = *(const float4*)&Bs[cw][il][4];
            const float4 C0 = *(const float4*)&Cs[cw][il][0];
            const float4 C1 = *(const float4*)&Cs[cw][il][4];
            sn[0] += uu*B0.x; sn[1] += uu*B0.y; sn[2] += uu*B0.z; sn[3] += uu*B0.w;
            sn[4] += uu*B1.x; sn[5] += uu*B1.y; sn[6] += uu*B1.z; sn[7] += uu*B1.w;
            gg[0] += w*C0.x;  gg[1] += w*C0.y;  gg[2] += w*C0.z;  gg[3] += w*C0.w;
            gg[4] += w*C1.x;  gg[5] += w*C1.y;  gg[6] += w*C1.z;  gg[7] += w*C1.w;
        }
        unsigned up[8];
        #pragma unroll
        for (int n = 0; n < 8; ++n) {
            unsigned pk = ((unsigned)f2bf(gg[n]) << 16) | f2bf(sn[n]);
            unsigned pv = (unsigned)__shfl_xor((int)pk, 16, 64);
            float psn = __uint_as_float(pv << 16);
            float pgg = __uint_as_float(pv & 0xffff0000u);
            up[n] = ((unsigned)f2bf(gg[n] + pgg) << 16) | f2bf(sn[n] + psn);
        }
        if ((quad & 1) == 0) {
            unsigned* dst = &SGg[((size_t)(bc0 + cw)*32 + h)*128 + mrow*8];
            *(uint4*)&dst[0] = *(uint4*)&up[0];
            *(uint4*)&dst[4] = *(uint4*)&up[4];
        }
    }
}

// ---------------------------------------------------------------------------
// A2 pass 1: element-parallel segmented scan (full batch). Zero barriers/LDS.
// ---------------------------------------------------------------------------
__global__ __launch_bounds__(128) void scanseg_kernel(
    const unsigned* __restrict__ SGg,  // [B*NC][32][128] packed
    const float* __restrict__ cdec,    // [B*NC][32]
    float* __restrict__ Sloc,          // [8192][128]
    float* __restrict__ Gseg,
    float* __restrict__ Aseg,
    float* __restrict__ ploc)          // [8192][16]
{
    const int blk = blockIdx.x;             // (b*32+h)*NSEG + seg
    const int seg = blk & (NSEG-1);
    const int bh  = blk >> 4;
    const int b = bh >> 5, h = bh & 31;
    const int tid = threadIdx.x;
    const int c0 = seg*SEG;

    float s = 0.f, P = 1.f, G = 0.f, pooled = 0.f;
    const unsigned* src = &SGg[((size_t)(b*NC + c0)*32 + h)*128 + tid];
    const float* dsrc = &cdec[(b*NC + c0)*32 + h];

    #pragma unroll 4
    for (int cc = 0; cc < SEG; ++cc) {
        unsigned u = src[(size_t)cc*4096];
        float d = dsrc[cc*32];
        float Sv = __uint_as_float(u << 16);
        float gv = __uint_as_float(u & 0xffff0000u);
        pooled += s * gv;
        G += P * gv;
        P *= d;
        s = s*d + Sv;
    }
    Sloc[(size_t)blk*128 + tid] = s;
    Gseg[(size_t)blk*128 + tid] = G;
    if (tid == 0) Aseg[blk] = P;

    float t = pooled;
    t += __shfl_down(t, 4, 8);
    t += __shfl_down(t, 2, 8);
    t += __shfl_down(t, 1, 8);
    if ((tid & 7) == 0) ploc[(size_t)blk*16 + (tid >> 3)] = t;
}

// ---------------------------------------------------------------------------
// A2 pass 2: combine NSEG segments per (b,h).
// ---------------------------------------------------------------------------
__global__ __launch_bounds__(128) void scancomb_kernel(
    const float* __restrict__ Sloc,
    const float* __restrict__ Gseg,
    const float* __restrict__ Aseg,
    const float* __restrict__ ploc,
    double* __restrict__ partial_inter) // [B][512]
{
    __shared__ double red[128];
    const int bh = blockIdx.x;              // b*32 + h
    const int tid = threadIdx.x;
    float s = 0.f;
    double acc = 0.0;
    for (int seg = 0; seg < NSEG; ++seg) {
        size_t base = (size_t)(bh*NSEG + seg);
        float Gv = Gseg[base*128 + tid];
        float Av = Aseg[base];
        float Sv = Sloc[base*128 + tid];
        acc += (double)(s * Gv);
        s = s*Av + Sv;
    }
    red[tid] = acc;
    __syncthreads();
    if (tid < 16) {
        double t = 0.0;
        #pragma unroll
        for (int n = 0; n < 8; ++n) t += red[tid*8 + n];
        for (int seg = 0; seg < NSEG; ++seg)
            t += (double)ploc[(size_t)(bh*NSEG + seg)*16 + tid];
        partial_inter[(size_t)bh*16 + tid] = t;
    }
}

// ---------------------------------------------------------------------------
__global__ __launch_bounds__(256) void reduce_intra_kernel(
    const float* __restrict__ pIn,     // [B*NC][512]
    float* __restrict__ pred)          // [B][32][512]
{
    const int g = blockIdx.x & 31;
    const int b = blockIdx.x >> 5;
    const int tid = threadIdx.x;
    for (int col = tid; col < 512; col += 256) {
        float s = 0.f;
        #pragma unroll 4
        for (int c = 0; c < 16; ++c)
            s += pIn[((size_t)b*NC + g*16 + c)*512 + col];
        pred[((size_t)(b*32) + g)*512 + col] = s;
    }
}

// ---------------------------------------------------------------------------
__global__ __launch_bounds__(512) void final_kernel(
    const float* __restrict__ pred,           // [B][32][512]
    const double* __restrict__ partial_inter, // [B][512]
    const float* __restrict__ W_oc,           // [6][512]
    const float* __restrict__ b_cls,          // [6]
    float* __restrict__ out)                  // [B][6]
{
    __shared__ double pooled[512];
    const int b = blockIdx.x, tid = threadIdx.x;
    double ssum = 0.0;
    for (int g = 0; g < 32; ++g)
        ssum += (double)pred[((size_t)(b*32) + g)*512 + tid];
    ssum += partial_inter[(size_t)b*512 + tid];
    pooled[tid] = ssum * (1.0/(double)SEQLEN);
    __syncthreads();
    if (tid < OUT_SIZE*64) {
        const int o = tid >> 6, l = tid & 63;
        double acc = 0.0;
        for (int m = l; m < 512; m += 64)
            acc += pooled[m] * (double)W_oc[o*512 + m];
        #pragma unroll
        for (int off = 32; off > 0; off >>= 1)
            acc += __shfl_down(acc, off);
        if (l == 0) out[b*OUT_SIZE + o] = (float)(acc + (double)b_cls[o]);
    }
}

// ---------------------------------------------------------------------------
extern "C" void kernel_launch(void* const* d_in, const int* in_sizes, int n_in,
                              void* d_out, int out_size, void* d_ws, size_t ws_size,
                              hipStream_t stream)
{
    const float* x        = (const float*)d_in[0];
    const float* W_in     = (const float*)d_in[1];
    const float* b_in     = (const float*)d_in[2];
    const float* W_inproj = (const float*)d_in[3];
    const float* conv_w   = (const float*)d_in[4];
    const float* conv_b   = (const float*)d_in[5];
    const float* dt_bias  = (const float*)d_in[6];
    const float* A_log    = (const float*)d_in[7];
    const float* Dvec     = (const float*)d_in[8];
    const float* W_out    = (const float*)d_in[9];
    const float* W_cls    = (const float*)d_in[10];
    const float* b_cls    = (const float*)d_in[11];
    float* out = (float*)d_out;

    char* ws = (char*)d_ws;
    size_t off = 0;
    auto alloc = [&](size_t bytes) -> void* {
        void* p = ws + off;
        off += (bytes + 255) & ~(size_t)255;
        return p;
    };
    unsigned* SGg = (unsigned*)alloc((size_t)BATCH*NC*32*128*4);        // 134.2 MB
    float*  cdecb = (float*) alloc((size_t)BATCH*NC*32*4);              // 1.0 MB
    float*  pIn   = (float*) alloc((size_t)BATCH*NC*512*4);             // 16.8 MB
    float*  SlocB = (float*) alloc((size_t)BATCH*NHEADS*NSEG*128*4);    // 4.2 MB
    float*  GsegB = (float*) alloc((size_t)BATCH*NHEADS*NSEG*128*4);    // 4.2 MB
    float*  AsegB = (float*) alloc((size_t)BATCH*NHEADS*NSEG*4);
    float*  plocB = (float*) alloc((size_t)BATCH*NHEADS*NSEG*16*4);     // 0.5 MB
    float*  pred  = (float*) alloc((size_t)BATCH*32*512*4);             // 1.0 MB
    double* pIt   = (double*)alloc((size_t)BATCH*512*8);                // 64 KB
    float*  WcT   = (float*) alloc((size_t)INPUT_DIM*D_INPROJ*4);
    float*  bcomb = (float*) alloc((size_t)D_INPROJ*4);
    unsigned short* Wbf = (unsigned short*)alloc((size_t)1024*64*2);    // 128 KB
    float*  Woc   = (float*) alloc((size_t)OUT_SIZE*D_INNER*4);
    if (off > ws_size) return;   // diagnostic: absmax-fail instead of fault

    precompute_kernel<<<D_INPROJ + D_INNER, 64, 0, stream>>>(W_in, b_in, W_inproj, W_out, W_cls,
                                                             WcT, bcomb, Wbf, Woc);
    fused_kernel<<<BATCH*NC/2, 256, 0, stream>>>(x, Wbf, WcT, bcomb, conv_w, conv_b,
                                                 dt_bias, A_log, Dvec, SGg, cdecb, pIn);
    scanseg_kernel<<<BATCH*NHEADS*NSEG, 128, 0, stream>>>(SGg, cdecb, SlocB, GsegB, AsegB, plocB);
    scancomb_kernel<<<BATCH*NHEADS, 128, 0, stream>>>(SlocB, GsegB, AsegB, plocB, pIt);
    reduce_intra_kernel<<<BATCH*32, 256, 0, stream>>>(pIn, pred);
    final_kernel<<<BATCH, 512, 0, stream>>>(pred, pIt, Woc, b_cls, out);
}

// Round 17
// 322.819 us; speedup vs baseline: 1.0851x; 1.0204x over previous
//
#include <hip/hip_runtime.h>
#include <math.h>

#define BATCH 16
#define SEQLEN 4096
#define INPUT_DIM 57
#define D_MODEL 256
#define D_INNER 512
#define D_STATE 8
#define HEADDIM 16
#define NHEADS 32
#define CHUNK 8
#define NC (SEQLEN/CHUNK)          // 512
#define CONV_DIM 528
#define D_INPROJ 1072
#define OUT_SIZE 6
#define NTOK (BATCH*SEQLEN)        // 65536
#define SEG 32                     // chunks per scan segment
#define NSEG (NC/SEG)              // 16

static __device__ const int tri_i_tab[36] = {0,1,1,2,2,2,3,3,3,3,4,4,4,4,4,5,5,5,5,5,5,6,6,6,6,6,6,6,7,7,7,7,7,7,7,7};
static __device__ const int tri_j_tab[36] = {0,0,1,0,1,2,0,1,2,3,0,1,2,3,4,0,1,2,3,4,5,0,1,2,3,4,5,6,0,1,2,3,4,5,6,7};

__device__ __forceinline__ unsigned short f2bf(float f) {   // RNE bf16, finite
    unsigned v = __float_as_uint(f);
    return (unsigned short)((v + 0x7fffu + ((v >> 16) & 1u)) >> 16);
}
__device__ __forceinline__ float fsilu(float v) {
    // v / (1+e^-v) with v_rcp_f32 instead of IEEE div (saves ~8 VALU inst)
    return v * __builtin_amdgcn_rcpf(1.f + __expf(-v));
}

typedef __attribute__((ext_vector_type(8))) short bf16x8;
typedef __attribute__((ext_vector_type(4))) float f32x4;

// ---------------------------------------------------------------------------
// P0: fold W_in into W_inproj; fold W_out into W_cls; emit bf16 Wbf[n][k].
// ---------------------------------------------------------------------------
__global__ void precompute_kernel(const float* __restrict__ W_in,
                                  const float* __restrict__ b_in,
                                  const float* __restrict__ W_inproj,
                                  const float* __restrict__ W_out,
                                  const float* __restrict__ W_cls,
                                  float* __restrict__ WcT,    // [57][1072]
                                  float* __restrict__ b_comb, // [1072]
                                  unsigned short* __restrict__ Wbf, // [1024][64]
                                  float* __restrict__ W_oc)   // [6][512]
{
    int blk = blockIdx.x;
    int t = threadIdx.x;
    if (blk < D_INPROJ) {
        int n = blk;
        if (t < INPUT_DIM) {
            double acc = 0.0;
            for (int m = 0; m < D_MODEL; ++m)
                acc += (double)W_inproj[n*D_MODEL+m] * (double)W_in[m*INPUT_DIM+t];
            WcT[t*D_INPROJ + n] = (float)acc;
            if (n < 1024) Wbf[n*64 + t] = f2bf((float)acc);
        } else {
            if (t == INPUT_DIM) {
                double acc = 0.0;
                for (int m = 0; m < D_MODEL; ++m)
                    acc += (double)W_inproj[n*D_MODEL+m] * (double)b_in[m];
                b_comb[n] = (float)acc;
            }
            if (n < 1024 && t < 64) Wbf[n*64 + t] = 0;   // k pad 57..63
        }
    } else {
        int d = blk - D_INPROJ;
        if (t < OUT_SIZE) {
            double acc = 0.0;
            for (int m = 0; m < D_MODEL; ++m)
                acc += (double)W_cls[t*D_MODEL+m] * (double)W_out[m*D_INNER+d];
            W_oc[t*D_INNER + d] = (float)acc;
        }
    }
}

// ---------------------------------------------------------------------------
// FUSED v2.4: R16 structure + fast-rcp silu (IEEE div was ~25% of VALU inst).
// ---------------------------------------------------------------------------
__global__ __launch_bounds__(256) void fused_kernel(
    const float* __restrict__ x,            // [NTOK][57]
    const unsigned short* __restrict__ Wbf, // [1024][64] bf16
    const float* __restrict__ WcT,          // [57][1072] fp32
    const float* __restrict__ bcomb,        // [1072]
    const float* __restrict__ conv_w,       // [528][4]
    const float* __restrict__ conv_b,       // [528]
    const float* __restrict__ dt_bias,      // [32]
    const float* __restrict__ A_log,        // [32]
    const float* __restrict__ Dvec,         // [32]
    unsigned* __restrict__ SGg,             // [B*NC][32][128] packed lo=S hi=g
    float* __restrict__ cdec,               // [B*NC][32]
    float* __restrict__ partial_intra)      // [B*NC][512]
{
    union SU {   // xs dead after A-frag load + phase 2b; tables written in 4b
        float xs[32][68];                               // 8704 B
        struct { float scl[2][36][33]; float gco[2][8][33]; } t; // 11616 B
    };
    __shared__ __attribute__((aligned(16))) SU u;
    __shared__ float ex[19][48];               // B/C/dt fp32, rows t0-3..t0+15
    __shared__ __attribute__((aligned(16))) float Bs[2][8][12], Cs[2][8][12];
    __shared__ float dts[2][8][33], cAl[2][8][33], els[2][8][33];
    __shared__ float CBl[2][8][8];

    const int blk = blockIdx.x;
    const int b = blk >> 8, cp = blk & 255;
    const int bc0 = (b << 9) + cp*2;           // chunk index of chunk 0
    const int tid = threadIdx.x;
    const long t0 = (long)b*SEQLEN + (long)cp*16;
    const bool first = (cp == 0);

    // ---- phase 1: stage 32 x rows (t0-16 .. t0+15), k padded ----
    #pragma unroll
    for (int it = 0; it < 8; ++it) {
        int idx = tid + it*256;
        int r = idx >> 6, k = idx & 63;
        float v = 0.f;
        if (k < INPUT_DIM && (r >= 16 || !first))
            v = x[(t0 - 16 + r)*INPUT_DIM + k];
        u.xs[r][k] = v;
    }
    __syncthreads();

    const int lane = tid & 63, wv = tid >> 6;
    const int quad = lane >> 4, mrow = lane & 15;

    // A fragments (regs; survive table overwrite of xs)
    bf16x8 aM[2], aH[2];
    #pragma unroll
    for (int hf = 0; hf < 2; ++hf) {
        const float* sm = &u.xs[16 + mrow][hf*32 + quad*8];
        const float* sh = &u.xs[mrow][hf*32 + quad*8];
        #pragma unroll
        for (int j = 0; j < 8; ++j) {
            aM[hf][j] = (short)f2bf(sm[j]);
            aH[hf][j] = (short)f2bf(sh[j]);
        }
    }

    // ---- phase 2b: fp32 extras (48 cols x 19 rows, K=57) ----
    if (tid < 192) {
        const int col = tid % 48;
        const int grp = tid / 48;              // 0..3
        const int r0 = grp*5;
        const int nr = (grp == 3) ? 4 : 5;
        const float be = bcomb[1024 + col];
        float a[5];
        #pragma unroll
        for (int j = 0; j < 5; ++j) a[j] = be;
        for (int k = 0; k < INPUT_DIM; ++k) {
            const float w = WcT[(size_t)k*D_INPROJ + 1024 + col];
            #pragma unroll
            for (int j = 0; j < 5; ++j)
                if (j < nr) a[j] += w*u.xs[13 + r0 + j][k];
        }
        #pragma unroll
        for (int j = 0; j < 5; ++j) {
            if (j < nr) {
                int r = r0 + j;
                ex[r][col] = (first && r < 3) ? 0.f : a[j];
            }
        }
    }
    __syncthreads();   // ex visible; xs reads done (A-frags in regs)

    // ---- phase 3: B/C conv+silu (32 lanes) and dt chain (64 lanes) ----
    if (tid < 32) {
        const int cw = tid >> 4, q = tid & 15;
        const int ch = 512 + q;
        const float4 cw4 = *(const float4*)&conv_w[ch*4];
        const float cb = conv_b[ch];
        float s0 = ex[cw*8+0][q], s1 = ex[cw*8+1][q], s2 = ex[cw*8+2][q];
        #pragma unroll
        for (int i = 0; i < 8; ++i) {
            float s3 = ex[cw*8+i+3][q];
            float v = cb + s0*cw4.x + s1*cw4.y + s2*cw4.z + s3*cw4.w;
            v = fsilu(v);
            if (q < 8) Bs[cw][i][q] = v; else Cs[cw][i][q-8] = v;
            s0 = s1; s1 = s2; s2 = s3;
        }
    } else if (tid >= 64 && tid < 128) {
        const int cw = (tid - 64) >> 5, h = (tid - 64) & 31;
        const float Ah = -__expf(A_log[h]);
        const float db = dt_bias[h];
        float ca = 0.f, e = 1.f;
        #pragma unroll
        for (int i = 0; i < 8; ++i) {
            float raw = ex[cw*8 + i + 3][16 + h] + db;
            float dt = (raw > 20.f) ? raw : log1pf(__expf(raw));
            dts[cw][i][h] = dt;
            ca += dt * Ah;
            cAl[cw][i][h] = ca;
            e = __expf(ca);
            els[cw][i][h] = e;
        }
        cdec[(bc0+cw)*32 + h] = e;
    }
    __syncthreads();

    // ---- phase 4: CB = C B^T per chunk ----
    if (tid < 128) {
        const int cw = tid >> 6, i = (tid >> 3) & 7, j = tid & 7;
        float s = 0.f;
        #pragma unroll
        for (int n = 0; n < 8; ++n) s += Cs[cw][i][n]*Bs[cw][j][n];
        CBl[cw][i][j] = s;
    }
    __syncthreads();

    // ---- phase 4b: coefficient tables (scl triangle + gco), into union ----
    #pragma unroll
    for (int q = 0; q < 9; ++q) {
        int idx = tid + q*256;                 // 2304 = 2*36*32
        int cw2 = idx / 1152, rem = idx - cw2*1152;
        int pr = rem >> 5, h2 = rem & 31;
        int i = tri_i_tab[pr], j = tri_j_tab[pr];
        u.t.scl[cw2][pr][h2] = CBl[cw2][i][j]
            * __expf(cAl[cw2][i][h2] - cAl[cw2][j][h2]) * dts[cw2][j][h2];
    }
    #pragma unroll
    for (int q = 0; q < 2; ++q) {
        int idx = tid + q*256;                 // 512 = 2*8*32
        int cw2 = idx >> 8, rem = idx & 255;
        int j = rem >> 5, h2 = rem & 31;
        u.t.gco[cw2][j][h2] = __expf(cAl[cw2][7][h2] - cAl[cw2][j][h2]) * dts[cw2][j][h2];
    }
    __syncthreads();

    // ---- phase 5: barrier-free tile loop. Lane owns z col `col` and x col
    // `col+512`, rows quad*4..quad*4+3. cw = quad>>1; joff = (quad&1)*4. ----
    const int cw   = quad >> 1;
    const int joff = (quad & 1) * 4;
    const int srcConv = (lane + 48) & 63;      // lane - 16 (mod 64)

    #pragma unroll
    for (int t = 0; t < 8; ++t) {
        const int g   = wv + 4*t;              // 0..31 = head h
        const int h   = g;
        const int col = g*16 + mrow;           // z col; x col = col+512

        // z MFMA
        const unsigned short* wpz = &Wbf[(size_t)col*64];
        bf16x8 bz0 = *(const bf16x8*)&wpz[quad*8];
        bf16x8 bz1 = *(const bf16x8*)&wpz[32 + quad*8];
        const float bvz = bcomb[col];
        f32x4 accZ; accZ.x = bvz; accZ.y = bvz; accZ.z = bvz; accZ.w = bvz;
        accZ = __builtin_amdgcn_mfma_f32_16x16x32_bf16(aM[0], bz0, accZ, 0, 0, 0);
        accZ = __builtin_amdgcn_mfma_f32_16x16x32_bf16(aM[1], bz1, accZ, 0, 0, 0);

        // x MFMA: main + halo
        const unsigned short* wpx = &Wbf[(size_t)(col + 512)*64];
        bf16x8 bx0 = *(const bf16x8*)&wpx[quad*8];
        bf16x8 bx1 = *(const bf16x8*)&wpx[32 + quad*8];
        const float bvx = bcomb[col + 512];
        f32x4 accXM; accXM.x = bvx; accXM.y = bvx; accXM.z = bvx; accXM.w = bvx;
        accXM = __builtin_amdgcn_mfma_f32_16x16x32_bf16(aM[0], bx0, accXM, 0, 0, 0);
        accXM = __builtin_amdgcn_mfma_f32_16x16x32_bf16(aM[1], bx1, accXM, 0, 0, 0);
        f32x4 accXH; accXH.x = bvx; accXH.y = bvx; accXH.z = bvx; accXH.w = bvx;
        accXH = __builtin_amdgcn_mfma_f32_16x16x32_bf16(aH[0], bx0, accXH, 0, 0, 0);
        accXH = __builtin_amdgcn_mfma_f32_16x16x32_bf16(aH[1], bx1, accXH, 0, 0, 0);

        // conv halo: consumer quad q gets rows 4q-1,-2,-3 from lane-16
        float s1 = (quad == 3) ? accXH[3] : accXM[3];
        float s2 = (quad == 3) ? accXH[2] : accXM[2];
        float s3 = (quad == 3) ? accXH[1] : accXM[1];
        float r1 = __shfl(s1, srcConv, 64);
        float r2 = __shfl(s2, srcConv, 64);
        float r3 = __shfl(s3, srcConv, 64);
        if (first && quad == 0) { r1 = 0.f; r2 = 0.f; r3 = 0.f; }

        const float4 cw4 = *(const float4*)&conv_w[col*4];   // conv channel = col
        const float cb = conv_b[col];
        float vals[7] = {r3, r2, r1, accXM[0], accXM[1], accXM[2], accXM[3]};
        float xv[4], szv[4];
        #pragma unroll
        for (int r = 0; r < 4; ++r) {
            float v = cb + vals[r]*cw4.x + vals[r+1]*cw4.y + vals[r+2]*cw4.z + vals[r+3]*cw4.w;
            xv[r] = fsilu(v);
            szv[r] = fsilu(accZ[r]);
        }

        // attention partials for all 8 chunk rows over own 4 j's
        float part[8];
        #pragma unroll
        for (int i = 0; i < 8; ++i) {
            float p = 0.f;
            #pragma unroll
            for (int r = 0; r < 4; ++r) {
                int jl = joff + r;
                if (jl <= i)
                    p += u.t.scl[cw][(i*(i+1))/2 + jl][h] * xv[r];
            }
            part[i] = p;
        }

        // combine with quad partner; pooled intra
        const float Dv = Dvec[h];
        float pa = 0.f;
        #pragma unroll
        for (int r = 0; r < 4; ++r) {
            float mine   = (quad & 1) ? part[4+r] : part[r];
            float theirs = (quad & 1) ? part[r]   : part[4+r];
            float other  = __shfl_xor(theirs, 16, 64);
            float y = Dv*xv[r] + mine + other;
            pa += y * szv[r];
        }
        pa += __shfl_xor(pa, 16, 64);
        if ((quad & 1) == 0)
            partial_intra[(size_t)(bc0 + cw)*512 + col] = pa;

        // (S, g) partials: per-row float4 Bs/Cs reads (transient regs only)
        float sn[8], gg[8];
        #pragma unroll
        for (int n = 0; n < 8; ++n) { sn[n] = 0.f; gg[n] = 0.f; }
        #pragma unroll
        for (int r = 0; r < 4; ++r) {
            const int il = joff + r;
            float gc = u.t.gco[cw][il][h];
            float e  = els[cw][il][h];
            float w  = szv[r]*e;
            float uu = gc*xv[r];
            const float4 B0 = *(const float4*)&Bs[cw][il][0];
            const float4 B1 = *(const float4*)&Bs[cw][il][4];
            const float4 C0 = *(const float4*)&Cs[cw][il][0];
            const float4 C1 = *(const float4*)&Cs[cw][il][4];
            sn[0] += uu*B0.x; sn[1] += uu*B0.y; sn[2] += uu*B0.z; sn[3] += uu*B0.w;
            sn[4] += uu*B1.x; sn[5] += uu*B1.y; sn[6] += uu*B1.z; sn[7] += uu*B1.w;
            gg[0] += w*C0.x;  gg[1] += w*C0.y;  gg[2] += w*C0.z;  gg[3] += w*C0.w;
            gg[4] += w*C1.x;  gg[5] += w*C1.y;  gg[6] += w*C1.z;  gg[7] += w*C1.w;
        }
        unsigned up[8];
        #pragma unroll
        for (int n = 0; n < 8; ++n) {
            unsigned pk = ((unsigned)f2bf(gg[n]) << 16) | f2bf(sn[n]);
            unsigned pv = (unsigned)__shfl_xor((int)pk, 16, 64);
            float psn = __uint_as_float(pv << 16);
            float pgg = __uint_as_float(pv & 0xffff0000u);
            up[n] = ((unsigned)f2bf(gg[n] + pgg) << 16) | f2bf(sn[n] + psn);
        }
        if ((quad & 1) == 0) {
            unsigned* dst = &SGg[((size_t)(bc0 + cw)*32 + h)*128 + mrow*8];
            *(uint4*)&dst[0] = *(uint4*)&up[0];
            *(uint4*)&dst[4] = *(uint4*)&up[4];
        }
    }
}

// ---------------------------------------------------------------------------
// A2 pass 1: element-parallel segmented scan (full batch). Zero barriers/LDS.
// ---------------------------------------------------------------------------
__global__ __launch_bounds__(128) void scanseg_kernel(
    const unsigned* __restrict__ SGg,  // [B*NC][32][128] packed
    const float* __restrict__ cdec,    // [B*NC][32]
    float* __restrict__ Sloc,          // [8192][128]
    float* __restrict__ Gseg,
    float* __restrict__ Aseg,
    float* __restrict__ ploc)          // [8192][16]
{
    const int blk = blockIdx.x;             // (b*32+h)*NSEG + seg
    const int seg = blk & (NSEG-1);
    const int bh  = blk >> 4;
    const int b = bh >> 5, h = bh & 31;
    const int tid = threadIdx.x;
    const int c0 = seg*SEG;

    float s = 0.f, P = 1.f, G = 0.f, pooled = 0.f;
    const unsigned* src = &SGg[((size_t)(b*NC + c0)*32 + h)*128 + tid];
    const float* dsrc = &cdec[(b*NC + c0)*32 + h];

    #pragma unroll 4
    for (int cc = 0; cc < SEG; ++cc) {
        unsigned u = src[(size_t)cc*4096];
        float d = dsrc[cc*32];
        float Sv = __uint_as_float(u << 16);
        float gv = __uint_as_float(u & 0xffff0000u);
        pooled += s * gv;
        G += P * gv;
        P *= d;
        s = s*d + Sv;
    }
    Sloc[(size_t)blk*128 + tid] = s;
    Gseg[(size_t)blk*128 + tid] = G;
    if (tid == 0) Aseg[blk] = P;

    float t = pooled;
    t += __shfl_down(t, 4, 8);
    t += __shfl_down(t, 2, 8);
    t += __shfl_down(t, 1, 8);
    if ((tid & 7) == 0) ploc[(size_t)blk*16 + (tid >> 3)] = t;
}

// ---------------------------------------------------------------------------
// A2 pass 2: combine NSEG segments per (b,h).
// ---------------------------------------------------------------------------
__global__ __launch_bounds__(128) void scancomb_kernel(
    const float* __restrict__ Sloc,
    const float* __restrict__ Gseg,
    const float* __restrict__ Aseg,
    const float* __restrict__ ploc,
    double* __restrict__ partial_inter) // [B][512]
{
    __shared__ double red[128];
    const int bh = blockIdx.x;              // b*32 + h
    const int tid = threadIdx.x;
    float s = 0.f;
    double acc = 0.0;
    for (int seg = 0; seg < NSEG; ++seg) {
        size_t base = (size_t)(bh*NSEG + seg);
        float Gv = Gseg[base*128 + tid];
        float Av = Aseg[base];
        float Sv = Sloc[base*128 + tid];
        acc += (double)(s * Gv);
        s = s*Av + Sv;
    }
    red[tid] = acc;
    __syncthreads();
    if (tid < 16) {
        double t = 0.0;
        #pragma unroll
        for (int n = 0; n < 8; ++n) t += red[tid*8 + n];
        for (int seg = 0; seg < NSEG; ++seg)
            t += (double)ploc[(size_t)(bh*NSEG + seg)*16 + tid];
        partial_inter[(size_t)bh*16 + tid] = t;
    }
}

// ---------------------------------------------------------------------------
__global__ __launch_bounds__(256) void reduce_intra_kernel(
    const float* __restrict__ pIn,     // [B*NC][512]
    float* __restrict__ pred)          // [B][32][512]
{
    const int g = blockIdx.x & 31;
    const int b = blockIdx.x >> 5;
    const int tid = threadIdx.x;
    for (int col = tid; col < 512; col += 256) {
        float s = 0.f;
        #pragma unroll 4
        for (int c = 0; c < 16; ++c)
            s += pIn[((size_t)b*NC + g*16 + c)*512 + col];
        pred[((size_t)(b*32) + g)*512 + col] = s;
    }
}

// ---------------------------------------------------------------------------
__global__ __launch_bounds__(512) void final_kernel(
    const float* __restrict__ pred,           // [B][32][512]
    const double* __restrict__ partial_inter, // [B][512]
    const float* __restrict__ W_oc,           // [6][512]
    const float* __restrict__ b_cls,          // [6]
    float* __restrict__ out)                  // [B][6]
{
    __shared__ double pooled[512];
    const int b = blockIdx.x, tid = threadIdx.x;
    double ssum = 0.0;
    for (int g = 0; g < 32; ++g)
        ssum += (double)pred[((size_t)(b*32) + g)*512 + tid];
    ssum += partial_inter[(size_t)b*512 + tid];
    pooled[tid] = ssum * (1.0/(double)SEQLEN);
    __syncthreads();
    if (tid < OUT_SIZE*64) {
        const int o = tid >> 6, l = tid & 63;
        double acc = 0.0;
        for (int m = l; m < 512; m += 64)
            acc += pooled[m] * (double)W_oc[o*512 + m];
        #pragma unroll
        for (int off = 32; off > 0; off >>= 1)
            acc += __shfl_down(acc, off);
        if (l == 0) out[b*OUT_SIZE + o] = (float)(acc + (double)b_cls[o]);
    }
}

// ---------------------------------------------------------------------------
extern "C" void kernel_launch(void* const* d_in, const int* in_sizes, int n_in,
                              void* d_out, int out_size, void* d_ws, size_t ws_size,
                              hipStream_t stream)
{
    const float* x        = (const float*)d_in[0];
    const float* W_in     = (const float*)d_in[1];
    const float* b_in     = (const float*)d_in[2];
    const float* W_inproj = (const float*)d_in[3];
    const float* conv_w   = (const float*)d_in[4];
    const float* conv_b   = (const float*)d_in[5];
    const float* dt_bias  = (const float*)d_in[6];
    const float* A_log    = (const float*)d_in[7];
    const float* Dvec     = (const float*)d_in[8];
    const float* W_out    = (const float*)d_in[9];
    const float* W_cls    = (const float*)d_in[10];
    const float* b_cls    = (const float*)d_in[11];
    float* out = (float*)d_out;

    char* ws = (char*)d_ws;
    size_t off = 0;
    auto alloc = [&](size_t bytes) -> void* {
        void* p = ws + off;
        off += (bytes + 255) & ~(size_t)255;
        return p;
    };
    unsigned* SGg = (unsigned*)alloc((size_t)BATCH*NC*32*128*4);        // 134.2 MB
    float*  cdecb = (float*) alloc((size_t)BATCH*NC*32*4);              // 1.0 MB
    float*  pIn   = (float*) alloc((size_t)BATCH*NC*512*4);             // 16.8 MB
    float*  SlocB = (float*) alloc((size_t)BATCH*NHEADS*NSEG*128*4);    // 4.2 MB
    float*  GsegB = (float*) alloc((size_t)BATCH*NHEADS*NSEG*128*4);    // 4.2 MB
    float*  AsegB = (float*) alloc((size_t)BATCH*NHEADS*NSEG*4);
    float*  plocB = (float*) alloc((size_t)BATCH*NHEADS*NSEG*16*4);     // 0.5 MB
    float*  pred  = (float*) alloc((size_t)BATCH*32*512*4);             // 1.0 MB
    double* pIt   = (double*)alloc((size_t)BATCH*512*8);                // 64 KB
    float*  WcT   = (float*) alloc((size_t)INPUT_DIM*D_INPROJ*4);
    float*  bcomb = (float*) alloc((size_t)D_INPROJ*4);
    unsigned short* Wbf = (unsigned short*)alloc((size_t)1024*64*2);    // 128 KB
    float*  Woc   = (float*) alloc((size_t)OUT_SIZE*D_INNER*4);
    if (off > ws_size) return;   // diagnostic: absmax-fail instead of fault

    precompute_kernel<<<D_INPROJ + D_INNER, 64, 0, stream>>>(W_in, b_in, W_inproj, W_out, W_cls,
                                                             WcT, bcomb, Wbf, Woc);
    fused_kernel<<<BATCH*NC/2, 256, 0, stream>>>(x, Wbf, WcT, bcomb, conv_w, conv_b,
                                                 dt_bias, A_log, Dvec, SGg, cdecb, pIn);
    scanseg_kernel<<<BATCH*NHEADS*NSEG, 128, 0, stream>>>(SGg, cdecb, SlocB, GsegB, AsegB, plocB);
    scancomb_kernel<<<BATCH*NHEADS, 128, 0, stream>>>(SlocB, GsegB, AsegB, plocB, pIt);
    reduce_intra_kernel<<<BATCH*32, 256, 0, stream>>>(pIn, pred);
    final_kernel<<<BATCH, 512, 0, stream>>>(pred, pIt, Woc, b_cls, out);
}